// Round 13
// baseline (127.757 us; speedup 1.0000x reference)
//
#include <hip/hip_runtime.h>

#define NPTS 96
#define HID  64
#define RANK 32

typedef float f2 __attribute__((ext_vector_type(2)));

// ws layout (floats): trans[axis][n][f], f contiguous (128 B rows)
#define TR(axis, n) ((((axis) * NPTS) + (n)) * RANK)

// -------- Kernel 1: the 4 tiny MLPs -> trans[axis][n][f] --------
__global__ __launch_bounds__(64) void spinn_mlp(
    const float* __restrict__ t, const float* __restrict__ x,
    const float* __restrict__ y, const float* __restrict__ z,
    const float* __restrict__ W1, const float* __restrict__ b1,
    const float* __restrict__ W2, const float* __restrict__ b2,
    const float* __restrict__ W3, const float* __restrict__ b3,
    float* __restrict__ ws)
{
    const int n    = blockIdx.x;   // point 0..95
    const int axis = blockIdx.y;   // 0..3
    const int j    = threadIdx.x;  // 0..63

    const float* coords[4] = { t, x, y, z };
    const float c = coords[axis][n];

    __shared__ float h1[HID];
    __shared__ float h2[HID];

    h1[j] = tanhf(fmaf(c, W1[axis * HID + j], b1[axis * HID + j]));
    __syncthreads();

    float a = b2[axis * HID + j];
    #pragma unroll
    for (int k = 0; k < HID; ++k)
        a = fmaf(h1[k], W2[(axis * HID + k) * HID + j], a);
    h2[j] = tanhf(a);
    __syncthreads();

    if (j < RANK) {
        float o = b3[axis * RANK + j];
        #pragma unroll
        for (int k = 0; k < HID; ++k)
            o = fmaf(h2[k], W3[(axis * HID + k) * RANK + j], o);
        ws[TR(axis, n) + j] = o;   // trans [axis][n][f]
    }
}

// -------- Kernel 2: R6 inner loop, persistent blocks, address-major tiles ---
// Tile space: (tt, yb, xq) = 96 x 24 x 4 = 9216 tiles.
// 576 blocks x 16 iters = 9216 (exact coverage; R12's bug was 4x short).
// Address-major id -> resident blocks sweep ~6 contiguous t-planes in
// lockstep; ~7 waves/CU -> ~1/4 the interleaved store streams of R6.
// Inner loop identical to R6: q2 = (ft*fy)(x)fz register-folded; per-x only
// fx row (uniform -> scalar K$ loads) + 32 pk-fma + one nt f2 store.
__global__ __launch_bounds__(192, 4) void spinn_recon(
    const float* __restrict__ ws, float* __restrict__ out)
{
    const int tid = threadIdx.x;       // 0..191
    const int zp  = tid % 48;          // z pair index
    const int yq  = tid / 48;          // 0..3
    const int z0  = zp * 2;

    const float* fzP = ws + TR(3, 0);
    const float* fxT = ws + TR(1, 0);

    #pragma unroll 1
    for (int r = 0; r < 16; ++r) {
        const int id = r * 576 + blockIdx.x;   // 0..9215, address-major
        const int tt = id / 96;                // 0..95
        const int w  = id % 96;
        const int yb = w / 4;                  // 0..23
        const int xq = w % 4;                  // 0..3
        const int yy = yb * 4 + yq;
        const int x0 = xq * 24;

        const float* ftT = ws + TR(0, tt);
        const float* fyT = ws + TR(2, yy);

        // q2[k][zz] = ( g0*fz[z0+zz][2k], g1*fz[z0+zz][2k+1] ), g = ft*fy
        f2 q2[16][2];
        #pragma unroll
        for (int k = 0; k < 16; ++k) {
            const f2 ft2 = *(const f2*)(ftT + 2 * k);
            const f2 fy2 = *(const f2*)(fyT + 2 * k);
            const f2 g   = ft2 * fy2;
            const f2 za  = *(const f2*)(fzP + (size_t)z0 * RANK + 2 * k);
            const f2 zb  = *(const f2*)(fzP + (size_t)(z0 + 1) * RANK + 2 * k);
            q2[k][0] = f2{ g.x * za.x, g.y * za.y };
            q2[k][1] = f2{ g.x * zb.x, g.y * zb.y };
        }

        float* outp = out + (size_t)tt * NPTS * NPTS * NPTS
                          + (size_t)x0 * NPTS * NPTS
                          + (size_t)yy * NPTS + z0;

        #pragma unroll 2
        for (int xs = 0; xs < 24; ++xs) {
            const f2* fp = (const f2*)(fxT + (size_t)(x0 + xs) * RANK); // uniform
            f2 a0 = { 0.f, 0.f }, a1 = { 0.f, 0.f };
            #pragma unroll
            for (int k = 0; k < 16; ++k) {
                const f2 p = fp[k];                  // (fx[2k], fx[2k+1])
                a0 = __builtin_elementwise_fma(p, q2[k][0], a0);
                a1 = __builtin_elementwise_fma(p, q2[k][1], a1);
            }
            const f2 rr = { a0.x + a0.y, a1.x + a1.y };
            __builtin_nontemporal_store(rr, (f2*)outp);
            outp += NPTS * NPTS;
        }
    }
}

extern "C" void kernel_launch(void* const* d_in, const int* in_sizes, int n_in,
                              void* d_out, int out_size, void* d_ws, size_t ws_size,
                              hipStream_t stream)
{
    const float* t  = (const float*)d_in[0];
    const float* x  = (const float*)d_in[1];
    const float* y  = (const float*)d_in[2];
    const float* z  = (const float*)d_in[3];
    const float* W1 = (const float*)d_in[4];
    const float* b1 = (const float*)d_in[5];
    const float* W2 = (const float*)d_in[6];
    const float* b2 = (const float*)d_in[7];
    const float* W3 = (const float*)d_in[8];
    const float* b3 = (const float*)d_in[9];

    float* ws  = (float*)d_ws;
    float* out = (float*)d_out;

    spinn_mlp<<<dim3(NPTS, 4), 64, 0, stream>>>(t, x, y, z, W1, b1, W2, b2, W3, b3, ws);
    spinn_recon<<<576, 192, 0, stream>>>(ws, out);
}

// Round 14
// 104.500 us; speedup vs baseline: 1.2226x; 1.2226x over previous
//
#include <hip/hip_runtime.h>

#define NPTS 96
#define HID  64
#define RANK 32

typedef float f2 __attribute__((ext_vector_type(2)));

// ws layout (floats): trans[axis][n][f], f contiguous (128 B rows)
#define TR(axis, n) ((((axis) * NPTS) + (n)) * RANK)

// -------- Kernel 1: the 4 tiny MLPs -> trans[axis][n][f] --------
__global__ __launch_bounds__(64) void spinn_mlp(
    const float* __restrict__ t, const float* __restrict__ x,
    const float* __restrict__ y, const float* __restrict__ z,
    const float* __restrict__ W1, const float* __restrict__ b1,
    const float* __restrict__ W2, const float* __restrict__ b2,
    const float* __restrict__ W3, const float* __restrict__ b3,
    float* __restrict__ ws)
{
    const int n    = blockIdx.x;   // point 0..95
    const int axis = blockIdx.y;   // 0..3
    const int j    = threadIdx.x;  // 0..63

    const float* coords[4] = { t, x, y, z };
    const float c = coords[axis][n];

    __shared__ float h1[HID];
    __shared__ float h2[HID];

    h1[j] = tanhf(fmaf(c, W1[axis * HID + j], b1[axis * HID + j]));
    __syncthreads();

    float a = b2[axis * HID + j];
    #pragma unroll
    for (int k = 0; k < HID; ++k)
        a = fmaf(h1[k], W2[(axis * HID + k) * HID + j], a);
    h2[j] = tanhf(a);
    __syncthreads();

    if (j < RANK) {
        float o = b3[axis * RANK + j];
        #pragma unroll
        for (int k = 0; k < HID; ++k)
            o = fmaf(h2[k], W3[(axis * HID + k) * RANK + j], o);
        ws[TR(axis, n) + j] = o;   // trans [axis][n][f]
    }
}

// -------- Kernel 2: dense-front reconstruction (fill-clone schedule) -------
// 1024 blocks x 9 grid-stride iters = 9216 (t,x) planes; 4 blocks/CU resident,
// all blocks advance in lockstep -> chip-wide ~36 MB dense write window that
// sweeps the output (the fill kernel's pattern). Block writes one plane =
// 36 KB contiguous per iter. Wave = one y-row (fy row wave-uniform -> scalar
// K$ loads, R6's proven operand path); lane = z-pair (48/64 active; wave
// store = exactly 3 full 128 B lines). q2 = (ft*fx) (.) fz register-folded
// per plane, amortized over 36 KB.
__global__ __launch_bounds__(256, 4) void spinn_recon(
    const float* __restrict__ ws, float* __restrict__ out)
{
    const int tid  = threadIdx.x;                       // 0..255
    const int w    = __builtin_amdgcn_readfirstlane(tid >> 6);  // wave 0..3
    const int lane = tid & 63;
    const int zp   = (lane < 48) ? lane : 47;           // clamp inactive lanes
    const int z0   = zp * 2;

    const float* fzR0 = ws + TR(3, z0);
    const float* fzR1 = ws + TR(3, z0 + 1);

    #pragma unroll 1
    for (int j = 0; j < 9; ++j) {
        const int p  = j * 1024 + blockIdx.x;   // plane 0..9215, address-major
        const int tt = p / 96;
        const int xx = p % 96;

        const float* ftR = ws + TR(0, tt);      // block-uniform
        const float* fxR = ws + TR(1, xx);      // block-uniform

        // q2[k][zz] = (ft*fx) pairs ⊙ fz[z0+zz] pairs   (64 VGPRs)
        f2 q2[16][2];
        #pragma unroll
        for (int k = 0; k < 16; ++k) {
            const f2 P = *(const f2*)(ftR + 2 * k) * *(const f2*)(fxR + 2 * k);
            q2[k][0] = P * *(const f2*)(fzR0 + 2 * k);
            q2[k][1] = P * *(const f2*)(fzR1 + 2 * k);
        }

        float* planep = out + (size_t)p * (NPTS * NPTS);

        #pragma unroll 2
        for (int i = 0; i < 24; ++i) {
            const int yy = i * 4 + w;                       // wave-uniform
            const f2* fy2 = (const f2*)(ws + TR(2, yy));    // scalar K$ loads
            f2 a0 = { 0.f, 0.f }, a1 = { 0.f, 0.f };
            #pragma unroll
            for (int k = 0; k < 16; ++k) {
                const f2 g = fy2[k];                        // (fy[2k], fy[2k+1])
                a0 = __builtin_elementwise_fma(g, q2[k][0], a0);
                a1 = __builtin_elementwise_fma(g, q2[k][1], a1);
            }
            const f2 r = { a0.x + a0.y, a1.x + a1.y };
            if (lane < 48)
                __builtin_nontemporal_store(r, (f2*)(planep + (size_t)yy * NPTS + z0));
        }
    }
}

extern "C" void kernel_launch(void* const* d_in, const int* in_sizes, int n_in,
                              void* d_out, int out_size, void* d_ws, size_t ws_size,
                              hipStream_t stream)
{
    const float* t  = (const float*)d_in[0];
    const float* x  = (const float*)d_in[1];
    const float* y  = (const float*)d_in[2];
    const float* z  = (const float*)d_in[3];
    const float* W1 = (const float*)d_in[4];
    const float* b1 = (const float*)d_in[5];
    const float* W2 = (const float*)d_in[6];
    const float* b2 = (const float*)d_in[7];
    const float* W3 = (const float*)d_in[8];
    const float* b3 = (const float*)d_in[9];

    float* ws  = (float*)d_ws;
    float* out = (float*)d_out;

    spinn_mlp<<<dim3(NPTS, 4), 64, 0, stream>>>(t, x, y, z, W1, b1, W2, b2, W3, b3, ws);
    spinn_recon<<<1024, 256, 0, stream>>>(ws, out);
}